// Round 6
// baseline (154.766 us; speedup 1.0000x reference)
//
#include <hip/hip_runtime.h>
#include <stdint.h>

typedef float f32x4 __attribute__((ext_vector_type(4)));
typedef _Float16 f16x8 __attribute__((ext_vector_type(8)));
typedef _Float16 f16x4 __attribute__((ext_vector_type(4)));
typedef int int4v __attribute__((ext_vector_type(4)));

#define LOG2E 1.44269504088896340736f

// global -> LDS direct copy, 16B per lane, wave-uniform LDS base (guide §5)
__device__ __forceinline__ void gload_lds16(const void* g, void* l) {
    auto gp = reinterpret_cast<const uint32_t __attribute__((address_space(1)))*>(
        reinterpret_cast<uintptr_t>(g));
    auto lp = reinterpret_cast<uint32_t __attribute__((address_space(3)))*>(
        reinterpret_cast<uintptr_t>(l));
    __builtin_amdgcn_global_load_lds(gp, lp, 16, 0, 0);
}

// ---------------- prep: pure f32->f16 converts ----------------
__global__ __launch_bounds__(256) void mega_prep(
    const float* __restrict__ roi_feat, const float* __restrict__ ref_feat,
    const float* __restrict__ Wg_w, const float* __restrict__ Wq_w,
    const float* __restrict__ Wk_w, const float* __restrict__ Wv_w,
    _Float16* __restrict__ roi_h, _Float16* __restrict__ ref_h,
    _Float16* __restrict__ wq_h, _Float16* __restrict__ wk_h,
    _Float16* __restrict__ wv_h, _Float16* __restrict__ wg_h)
{
    int idx = blockIdx.x * 256 + threadIdx.x;   // grid 5633*256 == 1442048 exactly
    const float* src; _Float16* dst; int off;
    if (idx < 131072)       { src = roi_feat; dst = roi_h; off = idx; }
    else if (idx < 655360)  { src = ref_feat; dst = ref_h; off = idx - 131072; }
    else if (idx < 917504)  { src = Wq_w;     dst = wq_h;  off = idx - 655360; }
    else if (idx < 1179648) { src = Wk_w;     dst = wk_h;  off = idx - 917504; }
    else if (idx < 1441792) { src = Wv_w;     dst = wv_h;  off = idx - 1179648; }
    else                    { src = Wg_w;     dst = wg_h;  off = idx - 1441792; }
    f32x4 v = *(const f32x4*)(src + (size_t)off * 4);
    f16x4 o;
    o[0] = (_Float16)v[0]; o[1] = (_Float16)v[1];
    o[2] = (_Float16)v[2]; o[3] = (_Float16)v[3];
    *(f16x4*)(dst + (size_t)off * 4) = o;
}

// ---------------- batched QKV GEMM: 128x128 tile, BK=64, double-buffered ----------------
// b<32:  Q = roi@Wq^T (+Wq_b+u)*0.125*log2e -> Qg [16][512][64]  (g-blocked)
// b<160: K = ref@Wk^T + Wk_b                -> Kg [16][2048][64] (g-blocked)
// b<288: V = ref@Wv'^T                      -> Vth [1024][2048]  (transposed)
__global__ __launch_bounds__(256, 2) void mega_gemm(
    const _Float16* __restrict__ roi_h, const _Float16* __restrict__ ref_h,
    const _Float16* __restrict__ wq_h, const _Float16* __restrict__ wk_h,
    const _Float16* __restrict__ wv_h,
    const float* __restrict__ Wq_b, const float* __restrict__ uvec,
    const float* __restrict__ Wk_b,
    _Float16* __restrict__ Qg, _Float16* __restrict__ Kg, _Float16* __restrict__ Vth)
{
    __shared__ __align__(16) _Float16 As[2][128 * 64];   // 2 x 16 KB
    __shared__ __align__(16) _Float16 Bs[2][128 * 64];   // 2 x 16 KB

    int b = blockIdx.x;
    const _Float16 *A, *B;
    _Float16* out;
    int tm, tn, mode; float scale;
    if (b < 32)       { A = roi_h; B = wq_h; out = Qg;  tm = b >> 3;        tn = b & 7;       mode = 0; scale = 0.125f * LOG2E; }
    else if (b < 160) { A = ref_h; B = wk_h; out = Kg;  tm = (b-32) >> 3;   tn = (b-32) & 7;  mode = 1; scale = 1.f; }
    else              { A = ref_h; B = wv_h; out = Vth; tm = (b-160) >> 3;  tn = (b-160) & 7; mode = 2; scale = 1.f; }
    int MR = (b < 32) ? 512 : 2048;

    int tid = threadIdx.x;
    int w = tid >> 6, l = tid & 63, q = l >> 4, t = l & 15;
    int wm = w >> 1, wn = w & 1;
    int m0 = tm * 128, n0 = tn * 128;

    // staging: rows r_lo(+32,+64,+96), 16B chunk c8; swizzle on global source (rule 21)
    int r_lo = tid >> 3, c8 = tid & 7;
    int swz = (c8 * 16) ^ ((r_lo & 7) << 4);
    const char* gA = (const char*)A + (size_t)(m0 + r_lo) * 2048 + swz;
    const char* gB = (const char*)B + (size_t)(n0 + r_lo) * 2048 + swz;
    char* lA = (char*)&As[0][0] + (w * 8) * 128;   // wave-uniform base
    char* lB = (char*)&Bs[0][0] + (w * 8) * 128;

#define GSTAGE(bufi, kt) { \
    size_t ko = (size_t)(kt) * 128; \
    gload_lds16(gA + ko,           lA + (bufi)*16384); \
    gload_lds16(gA + ko + 32*2048, lA + (bufi)*16384 + 4096); \
    gload_lds16(gA + ko + 64*2048, lA + (bufi)*16384 + 8192); \
    gload_lds16(gA + ko + 96*2048, lA + (bufi)*16384 + 12288); \
    gload_lds16(gB + ko,           lB + (bufi)*16384); \
    gload_lds16(gB + ko + 32*2048, lB + (bufi)*16384 + 4096); \
    gload_lds16(gB + ko + 64*2048, lB + (bufi)*16384 + 8192); \
    gload_lds16(gB + ko + 96*2048, lB + (bufi)*16384 + 12288); }

    f32x4 acc[4][4];
    #pragma unroll
    for (int i = 0; i < 4; ++i)
        #pragma unroll
        for (int j = 0; j < 4; ++j)
            acc[i][j] = (f32x4){0.f, 0.f, 0.f, 0.f};

    GSTAGE(0, 0);
    __syncthreads();

    for (int kt = 0; kt < 16; ++kt) {
        int cur = kt & 1;
        if (kt < 15) GSTAGE(cur ^ 1, kt + 1);   // next tile's loads fly under compute

        const char* cA = (const char*)&As[0][0] + cur * 16384;
        const char* cB = (const char*)&Bs[0][0] + cur * 16384;
        f16x8 af[2][4], bf[2][4];
        #pragma unroll
        for (int mi = 0; mi < 4; ++mi) {
            int row = wm * 64 + mi * 16 + t;
            int sx = (row & 7) << 4;
            #pragma unroll
            for (int ks = 0; ks < 2; ++ks)
                af[ks][mi] = *(const f16x8*)(cA + row * 128 + ((ks * 64 + q * 16) ^ sx));
        }
        #pragma unroll
        for (int ni = 0; ni < 4; ++ni) {
            int row = wn * 64 + ni * 16 + t;
            int sx = (row & 7) << 4;
            #pragma unroll
            for (int ks = 0; ks < 2; ++ks)
                bf[ks][ni] = *(const f16x8*)(cB + row * 128 + ((ks * 64 + q * 16) ^ sx));
        }
        __builtin_amdgcn_s_setprio(1);
        #pragma unroll
        for (int ks = 0; ks < 2; ++ks)
            #pragma unroll
            for (int mi = 0; mi < 4; ++mi)
                #pragma unroll
                for (int ni = 0; ni < 4; ++ni)
                    acc[mi][ni] = __builtin_amdgcn_mfma_f32_16x16x32_f16(af[ks][mi], bf[ks][ni], acc[mi][ni], 0, 0, 0);
        __builtin_amdgcn_s_setprio(0);
        __syncthreads();   // drains stage loads; guards buffer reuse
    }
#undef GSTAGE

    #pragma unroll
    for (int mi = 0; mi < 4; ++mi) {
        #pragma unroll
        for (int ni = 0; ni < 4; ++ni) {
            int col  = n0 + wn*64 + ni*16 + t;
            int row0 = m0 + wm*64 + mi*16 + q*4;
            f32x4 a = acc[mi][ni];
            if (mode == 2) {
                f16x4 pk;
                pk[0] = (_Float16)a[0]; pk[1] = (_Float16)a[1];
                pk[2] = (_Float16)a[2]; pk[3] = (_Float16)a[3];
                *(f16x4*)(out + (size_t)col * 2048 + row0) = pk;
            } else {
                float bb = (mode == 0) ? (Wq_b[col] + uvec[col]) : Wk_b[col];
                _Float16* op = out + ((size_t)(col >> 6) * MR + row0) * 64 + (col & 63);
                #pragma unroll
                for (int rr = 0; rr < 4; ++rr)
                    op[(size_t)rr * 64] = (_Float16)((a[rr] + bb) * scale);
            }
        }
    }
}

// ---------------- position prior: relu(Wg @ emb + Wg_b), via MFMA ----------------
// output layout [g][n][m] f16: prior[g*512*2048 + n*2048 + m]
__global__ __launch_bounds__(256) void mega_prior(
    const _Float16* __restrict__ wg_h, const float* __restrict__ Wg_b,
    const float* __restrict__ bbox, const float* __restrict__ ref_bbox,
    _Float16* __restrict__ prior)
{
    int tid = threadIdx.x;
    int w = tid >> 6, l = tid & 63, q = l >> 4, p = l & 15;
    int n = blockIdx.x >> 1, half = blockIdx.x & 1;

    f16x8 wa0 = *(const f16x8*)(wg_h + p*64 + q*8);
    f16x8 wa1 = *(const f16x8*)(wg_h + p*64 + 32 + q*8);
    f32x4 wb = *(const f32x4*)(Wg_b + q*4);

    f32x4 bbx = *(const f32x4*)(bbox + n * 4);
    float bw = bbx[2] - bbx[0] + 1.0f, bh = bbx[3] - bbx[1] + 1.0f;
    float cx = 0.5f*(bbx[0]+bbx[2]), cy = 0.5f*(bbx[1]+bbx[3]);

    float cf[8];
    #pragma unroll
    for (int f = 0; f < 8; ++f)
        cf[f] = 15.9154943091895336f * __builtin_exp2f(-1.24572303558276059f * (float)f);

    float coff = (q & 1) ? 0.25f : 0.0f;   // cos(x) = sin(x + 1/4 rev)
    bool isX = (q < 2);
    float cA   = isX ? cx : cy;
    float invA = isX ? 1.0f/bw : 1.0f/bh;
    float lgA  = isX ? __logf(bw) : __logf(bh);

    int mstart = half * 1024 + w * 256;
    for (int it = 0; it < 16; ++it) {
        int m = mstart + it * 16 + p;
        f32x4 rb = *(const f32x4*)(ref_bbox + m * 4);
        float cAr = isX ? 0.5f*(rb[0]+rb[2]) : 0.5f*(rb[1]+rb[3]);
        float sAr = isX ? (rb[2]-rb[0]+1.0f) : (rb[3]-rb[1]+1.0f);
        float posA = __logf(fabsf(cA - cAr) * invA + 1e-3f);
        float posB = lgA - __logf(sAr);
        f16x8 e0, e1;
        #pragma unroll
        for (int f = 0; f < 8; ++f) {
            float a0 = posA * cf[f] + coff; a0 -= floorf(a0);
            float a1 = posB * cf[f] + coff; a1 -= floorf(a1);
            e0[f] = (_Float16)__builtin_amdgcn_sinf(a0);
            e1[f] = (_Float16)__builtin_amdgcn_sinf(a1);
        }
        f32x4 acc = wb;
        acc = __builtin_amdgcn_mfma_f32_16x16x32_f16(wa0, e0, acc, 0, 0, 0);
        acc = __builtin_amdgcn_mfma_f32_16x16x32_f16(wa1, e1, acc, 0, 0, 0);
        _Float16* pp = prior + (size_t)n * 2048 + m;
        #pragma unroll
        for (int r = 0; r < 4; ++r)
            pp[(size_t)(q*4 + r) * 1048576] = (_Float16)fmaxf(acc[r], 0.f);
    }
}

// ---------------- flash attention, 8-wave blocks (g, 128 n, 256-m span) ----------------
// Per 64-m chunk: stage K[64][64], V^T[64][64], prior[128][64] into LDS
// (coalesced, XOR-swizzled, double-buffered). T14 async-split staging.
#define SWZ(row, cb) ((cb) ^ (((row) & 7) << 4))

__device__ __forceinline__ f16x8 ld128s(const _Float16* base, int row, int cb) {
    return *(const f16x8*)((const char*)base + row * 128 + SWZ(row, cb));
}
__device__ __forceinline__ f16x4 ld64s(const _Float16* base, int row, int cb) {
    return *(const f16x4*)((const char*)base + row * 128 + SWZ(row, cb));
}

__global__ __launch_bounds__(512, 4) void mega_attn(
    const _Float16* __restrict__ Qg, const _Float16* __restrict__ Kg,
    const _Float16* __restrict__ Vth, const _Float16* __restrict__ prior,
    _Float16* __restrict__ Opart, float* __restrict__ Mpart, float* __restrict__ Lpart)
{
    __shared__ __align__(16) _Float16 Kl[2][4096];   // 2 x 8 KB
    __shared__ __align__(16) _Float16 Vl[2][4096];   // 2 x 8 KB
    __shared__ __align__(16) _Float16 Pl[2][8192];   // 2 x 16 KB

    int bid = blockIdx.x;                 // 512 blocks: 16 g x 4 nt2 x 8 s
    int g = bid >> 5, nt2 = (bid >> 3) & 3, s = bid & 7;
    int tid = threadIdx.x;
    int w = tid >> 6, l = tid & 63, q = l >> 4, t = l & 15;
    int n0 = nt2 * 128, m0 = s * 256;

    int n = n0 + w * 16 + t;
    const _Float16* Qrow = Qg + ((size_t)g * 512 + n) * 64;
    f16x8 qf0 = *(const f16x8*)(Qrow + q * 8);
    f16x8 qf1 = *(const f16x8*)(Qrow + 32 + q * 8);

    // staging lane mapping: row r_lo = tid/8 (0..63), 16B chunk c8 = tid%8
    int r_lo = tid >> 3, c8 = tid & 7;
    const char* gK = (const char*)(Kg + ((size_t)g * 2048 + m0) * 64);
    const char* gV = (const char*)(Vth + (size_t)g * 64 * 2048 + m0);
    const char* gP = (const char*)(prior + ((size_t)g * 512 + n0) * 2048 + m0);

    int4v kr, vr, pq0, pq1;
#define LOADC(c) { \
    kr  = *(const int4v*)(gK + (c)*8192 + r_lo*128 + c8*16); \
    vr  = *(const int4v*)(gV + (c)*128 + (size_t)r_lo*4096 + c8*16); \
    pq0 = *(const int4v*)(gP + (c)*128 + (size_t)r_lo*4096 + c8*16); \
    pq1 = *(const int4v*)(gP + (c)*128 + (size_t)(r_lo+64)*4096 + c8*16); }
#define WRITEC(bufi) { \
    int sw = SWZ(r_lo, c8 * 16); \
    *(int4v*)((char*)&Kl[bufi][0] + r_lo*128 + sw) = kr; \
    *(int4v*)((char*)&Vl[bufi][0] + r_lo*128 + sw) = vr; \
    *(int4v*)((char*)&Pl[bufi][0] + r_lo*128 + sw) = pq0; \
    *(int4v*)((char*)&Pl[bufi][0] + (r_lo+64)*128 + sw) = pq1; }

    float mrow = -INFINITY, lsum = 0.f;
    f32x4 Ov[4] = {{0,0,0,0},{0,0,0,0},{0,0,0,0},{0,0,0,0}};

    LOADC(0);
    WRITEC(0);
    __syncthreads();

    for (int c = 0; c < 4; ++c) {
        int cur = c & 1;
        if (c < 3) LOADC(c + 1);   // issue early; lands during compute (T14)

        const _Float16* Kb_l = &Kl[cur][0];
        const _Float16* Vb_l = &Vl[cur][0];
        const _Float16* Pb_l = &Pl[cur][0];

        // QK^T with C=0
        f32x4 sv[4];
        __builtin_amdgcn_s_setprio(1);
        #pragma unroll
        for (int mi = 0; mi < 4; ++mi) {
            f16x8 k0 = ld128s(Kb_l, mi * 16 + t, q * 16);
            f16x8 k1 = ld128s(Kb_l, mi * 16 + t, 64 + q * 16);
            f32x4 z = {0, 0, 0, 0};
            z = __builtin_amdgcn_mfma_f32_16x16x32_f16(k0, qf0, z, 0, 0, 0);
            z = __builtin_amdgcn_mfma_f32_16x16x32_f16(k1, qf1, z, 0, 0, 0);
            sv[mi] = z;
        }
        __builtin_amdgcn_s_setprio(0);
        // + log2(prior + 1e-6), prior row = this wave's n row
        #pragma unroll
        for (int mi = 0; mi < 4; ++mi) {
            f16x4 pr = ld64s(Pb_l, w * 16 + t, mi * 32 + q * 8);
            #pragma unroll
            for (int r = 0; r < 4; ++r)
                sv[mi][r] += __log2f((float)pr[r] + 1e-6f);
        }
        // online softmax (log2 domain)
        float cmax = -INFINITY;
        #pragma unroll
        for (int mi = 0; mi < 4; ++mi)
            #pragma unroll
            for (int r = 0; r < 4; ++r)
                cmax = fmaxf(cmax, sv[mi][r]);
        cmax = fmaxf(cmax, __shfl_xor(cmax, 16));
        cmax = fmaxf(cmax, __shfl_xor(cmax, 32));
        float mnew = fmaxf(mrow, cmax);
        float corr = __builtin_exp2f(mrow - mnew);
        float psum = 0.f;
        f16x4 pf[4];
        #pragma unroll
        for (int mi = 0; mi < 4; ++mi) {
            #pragma unroll
            for (int r = 0; r < 4; ++r) {
                float pv = __builtin_exp2f(sv[mi][r] - mnew);
                psum += pv;
                pf[mi][r] = (_Float16)pv;
            }
        }
        psum += __shfl_xor(psum, 16);
        psum += __shfl_xor(psum, 32);
        lsum = lsum * corr + psum;
        mrow = mnew;
        #pragma unroll
        for (int i = 0; i < 4; ++i) Ov[i] *= corr;
        // PV: V-frags loaded per d-block (register-lean)
        __builtin_amdgcn_s_setprio(1);
        #pragma unroll
        for (int i = 0; i < 4; ++i) {
            #pragma unroll
            for (int mi = 0; mi < 4; ++mi) {
                f16x4 vv = ld64s(Vb_l, i * 16 + t, mi * 32 + q * 8);
                Ov[i] = __builtin_amdgcn_mfma_f32_16x16x16f16(vv, pf[mi], Ov[i], 0, 0, 0);
            }
        }
        __builtin_amdgcn_s_setprio(0);

        if (c < 3) WRITEC(cur ^ 1);   // ds-write next chunk (waits its loads)
        __syncthreads();
    }

    int u = ((g * 32 + nt2 * 8 + w) << 3) + s;
    size_t ob = (size_t)(u * 16 + t) * 64;
    #pragma unroll
    for (int i = 0; i < 4; ++i) {
        f16x4 ph;
        ph[0] = (_Float16)Ov[i][0]; ph[1] = (_Float16)Ov[i][1];
        ph[2] = (_Float16)Ov[i][2]; ph[3] = (_Float16)Ov[i][3];
        *(f16x4*)(Opart + ob + i * 16 + q * 4) = ph;
    }
    if (q == 0) { Mpart[u*16 + t] = mrow; Lpart[u*16 + t] = lsum; }
#undef LOADC
#undef WRITEC
}

// ---------------- combine 8 split-M partials, normalize, + Wv_b ----------------
__global__ __launch_bounds__(256) void mega_combine(
    const _Float16* __restrict__ Opart, const float* __restrict__ Mpart,
    const float* __restrict__ Lpart, const float* __restrict__ Wv_b,
    float* __restrict__ outp)
{
    int idx = blockIdx.x * 256 + threadIdx.x;
    int n = idx >> 10, col = idx & 1023;
    int g = col >> 6, d = col & 63;
    int nt = n >> 4, t = n & 15;
    int u0 = ((g * 32 + nt) << 3);
    float ms[8];
    #pragma unroll
    for (int s = 0; s < 8; ++s) ms[s] = Mpart[(u0 + s) * 16 + t];
    float M = ms[0];
    #pragma unroll
    for (int s = 1; s < 8; ++s) M = fmaxf(M, ms[s]);
    float accO = 0.f, accL = 0.f;
    #pragma unroll
    for (int s = 0; s < 8; ++s) {
        float wgt = __builtin_exp2f(ms[s] - M);
        accO += wgt * (float)Opart[(size_t)((u0 + s) * 16 + t) * 64 + d];
        accL += wgt * Lpart[(u0 + s) * 16 + t];
    }
    outp[idx] = accO / accL + Wv_b[col];
}

extern "C" void kernel_launch(void* const* d_in, const int* in_sizes, int n_in,
                              void* d_out, int out_size, void* d_ws, size_t ws_size,
                              hipStream_t stream)
{
    const float* bbox     = (const float*)d_in[0];
    const float* ref_bbox = (const float*)d_in[1];
    const float* roi_feat = (const float*)d_in[2];
    const float* ref_feat = (const float*)d_in[3];
    const float* Wg_w = (const float*)d_in[4];
    const float* Wg_b = (const float*)d_in[5];
    const float* Wq_w = (const float*)d_in[6];
    const float* Wq_b = (const float*)d_in[7];
    const float* Wk_w = (const float*)d_in[8];
    const float* Wk_b = (const float*)d_in[9];
    const float* Wv_w = (const float*)d_in[10];
    const float* Wv_b = (const float*)d_in[11];
    const float* uvec = (const float*)d_in[12];
    float* outp = (float*)d_out;
    char* ws = (char*)d_ws;

    _Float16* roi_h = (_Float16*)(ws + 0);
    _Float16* ref_h = (_Float16*)(ws + (1ull<<20));
    _Float16* wq_h  = (_Float16*)(ws + (5ull<<20));
    _Float16* wk_h  = (_Float16*)(ws + (7ull<<20));
    _Float16* wv_h  = (_Float16*)(ws + (9ull<<20));
    _Float16* wg_h  = (_Float16*)(ws + (11ull<<20));
    size_t b2 = 12ull<<20;
    _Float16* prior = (_Float16*)(ws + b2);                    // 32 MB
    size_t b3 = b2 + (32ull<<20);
    _Float16* Qh    = (_Float16*)(ws + b3);
    _Float16* Kh    = (_Float16*)(ws + b3 + (1ull<<20));
    _Float16* Vth   = (_Float16*)(ws + b3 + (5ull<<20));
    _Float16* Opart = (_Float16*)(ws + b3 + (9ull<<20));
    float* Mpart    = (float*)(ws + b3 + (25ull<<20));
    float* Lpart    = (float*)(ws + b3 + (25ull<<20) + 262144);

    mega_prep<<<5633, 256, 0, stream>>>(roi_feat, ref_feat,
        Wg_w, Wq_w, Wk_w, Wv_w,
        roi_h, ref_h, wq_h, wk_h, wv_h, wg_h);
    mega_gemm<<<288, 256, 0, stream>>>(roi_h, ref_h, wq_h, wk_h, wv_h,
        Wq_b, uvec, Wk_b, Qh, Kh, Vth);
    mega_prior<<<1024, 256, 0, stream>>>(wg_h, Wg_b, bbox, ref_bbox, prior);
    mega_attn<<<512, 512, 0, stream>>>(Qh, Kh, Vth, prior, Opart, Mpart, Lpart);
    mega_combine<<<2048, 256, 0, stream>>>(Opart, Mpart, Lpart, Wv_b, outp);
}